// Round 6
// baseline (222.660 us; speedup 1.0000x reference)
//
#include <hip/hip_runtime.h>

#define Bc 8
#define Tc 8
#define Cc 32
#define Hc 16
#define Wc 28
#define NHc 4
#define DKc 8
#define HWc (Hc*Wc)                  // 448
#define INV_SCALE 0.35355339059327373f
#define LN_EPSc 1e-5f

typedef _Float16 half8 __attribute__((ext_vector_type(8)));

// Workspace layouts:
//   Q     : [bh][t][j4][hw]    float4   (pre-scaled by INV_SCALE)
//   K,V   : [bh][s][hw][dk]    float
//   Tpart : [bh][s][t][hw]     half8
//   LM    : [bh][s][t][hw]     float2   (l = sum exp, m = max score)

// Device-wide barrier: valid because grid == 256 == #CUs and
// __launch_bounds__(448,4) caps VGPR at 128 -> >=2 blocks/CU capacity
// (LDS 57344*2 <= 160K, 14 waves <= 16), so all blocks are resident even
// under pathological packing.  Counter zeroed by hipMemsetAsync pre-launch.
__device__ __forceinline__ void gridbar(unsigned* cnt, unsigned target) {
    __syncthreads();
    if (threadIdx.x == 0) {
        __threadfence();   // release: flush this XCD's L2
        __hip_atomic_fetch_add(cnt, 1u, __ATOMIC_ACQ_REL, __HIP_MEMORY_SCOPE_AGENT);
        while (__hip_atomic_load(cnt, __ATOMIC_ACQUIRE, __HIP_MEMORY_SCOPE_AGENT) < target)
            __builtin_amdgcn_s_sleep(2);
        __threadfence();   // acquire: invalidate stale L1/L2 before reads
    }
    __syncthreads();
}

// ---------------------------------------------------------------------------
// One attention work item: (bh, s, t-half), t_batch = 4, K/V already in LDS.
// ---------------------------------------------------------------------------
__device__ __forceinline__ void attn_item(
    int bh, int dil, int s, int t0, int tid, int w, int h,
    const float4* sK0, const float4* sK1,
    const float4* sV0, const float4* sV1,
    const float4* __restrict__ Q,
    half8* __restrict__ Tpart, float2* __restrict__ LMpart)
{
    float4 q0[4], q1[4];
    const float4* qb = Q + (size_t)bh*Tc*2*HWc + tid;
#pragma unroll
    for (int j = 0; j < 4; ++j) {
        q0[j] = qb[((t0+j)*2+0)*HWc];
        q1[j] = qb[((t0+j)*2+1)*HWc];
    }

    float4 a0[4], a1[4];
    float l[4], m[4];
#pragma unroll
    for (int j = 0; j < 4; ++j) {
        a0[j] = make_float4(0.f,0.f,0.f,0.f);
        a1[j] = make_float4(0.f,0.f,0.f,0.f);
        l[j] = 0.f; m[j] = -1e30f;
    }

    for (int dy = -3; dy <= 3; ++dy) {
        int hy = h + dy*dil;
        if ((unsigned)hy >= (unsigned)Hc) continue;   // exec-mask row skip
        int rowbase = hy*Wc;
#pragma unroll
        for (int dx = -3; dx <= 3; ++dx) {
            int wx = w + dx*dil;
            int wcl = min(max(wx, 0), Wc-1);
            bool cv = (unsigned)wx < (unsigned)Wc;
            float bias = cv ? 0.f : -1e30f;
            float mask = cv ? 1.f : 0.f;
            int idx = rowbase + wcl;
            float4 k0 = sK0[idx], k1 = sK1[idx];
            float4 v0 = sV0[idx], v1 = sV1[idx];
#pragma unroll
            for (int j = 0; j < 4; ++j) {
                float sc = q0[j].x*k0.x + q0[j].y*k0.y + q0[j].z*k0.z + q0[j].w*k0.w
                         + q1[j].x*k1.x + q1[j].y*k1.y + q1[j].z*k1.z + q1[j].w*k1.w;
                float msc = sc + bias;
                m[j] = fmaxf(m[j], msc);
                l[j] += __expf(msc);
                float z = sc * mask;
                a0[j].x = fmaf(z, v0.x, a0[j].x);
                a0[j].y = fmaf(z, v0.y, a0[j].y);
                a0[j].z = fmaf(z, v0.z, a0[j].z);
                a0[j].w = fmaf(z, v0.w, a0[j].w);
                a1[j].x = fmaf(z, v1.x, a1[j].x);
                a1[j].y = fmaf(z, v1.y, a1[j].y);
                a1[j].z = fmaf(z, v1.z, a1[j].z);
                a1[j].w = fmaf(z, v1.w, a1[j].w);
            }
        }
    }

    half8*  tp  = Tpart  + (size_t)(bh*Tc + s)*Tc*HWc + tid;
    float2* lmp = LMpart + (size_t)(bh*Tc + s)*Tc*HWc + tid;
#pragma unroll
    for (int j = 0; j < 4; ++j) {
        half8 hv;
        hv[0] = (_Float16)a0[j].x; hv[1] = (_Float16)a0[j].y;
        hv[2] = (_Float16)a0[j].z; hv[3] = (_Float16)a0[j].w;
        hv[4] = (_Float16)a1[j].x; hv[5] = (_Float16)a1[j].y;
        hv[6] = (_Float16)a1[j].z; hv[7] = (_Float16)a1[j].w;
        tp [(t0+j)*HWc] = hv;
        lmp[(t0+j)*HWc] = make_float2(l[j], m[j]);
    }
}

// ---------------------------------------------------------------------------
// Fully fused persistent kernel.  grid = 256 blocks, 448 threads.
// Phase 1: qkv+LN   (block = head*64 + bt; XCD co-location of shared input)
// Phase 2: attention, complementary-head paired (block = (b,ha,s,g))
// Phase 3: combine + outproj (block = og*64 + bt)
// ---------------------------------------------------------------------------
__global__ __launch_bounds__(448, 4) void fused_kernel(
    const float* __restrict__ first, const float* __restrict__ x,
    const float* __restrict__ Wq, const float* __restrict__ Wk,
    const float* __restrict__ Wv, const float* __restrict__ Wo,
    const float* __restrict__ gamma, const float* __restrict__ beta,
    float* __restrict__ Qf, float* __restrict__ K, float* __restrict__ V,
    half8* __restrict__ Tpart, float2* __restrict__ LMpart,
    float* __restrict__ out, unsigned* __restrict__ cnt)
{
    int blk = blockIdx.x;
    int tid = threadIdx.x;

    __shared__ float4 sbuf[8*HWc];          // 57344 B, re-used per phase
    float* rbuf = (float*)sbuf;             // phase-1 LN reduction scratch

    // ================= Phase 1: QKV projection + LayerNorm(q) ==============
    {
        int head = blk >> 6;
        int bt   = blk & 63;
        int t    = bt & 7;
        int b    = bt >> 3;

        const float* fp = first + (size_t)bt * Cc * HWc + tid;
        const float* xp = x     + (size_t)bt * Cc * HWc + tid;

        float qv[DKc], kv[DKc], vv[DKc];
#pragma unroll
        for (int j = 0; j < DKc; ++j) { qv[j] = 0.f; kv[j] = 0.f; vv[j] = 0.f; }

        // c-chunked accumulation keeps VGPR low (<=128 for 2-block residency)
        for (int c0 = 0; c0 < Cc; c0 += 8) {
            float f8[8], x8[8];
#pragma unroll
            for (int j = 0; j < 8; ++j) {
                f8[j] = fp[(c0+j)*HWc];
                x8[j] = xp[(c0+j)*HWc];
            }
#pragma unroll
            for (int dk = 0; dk < DKc; ++dk) {
                int o = head*DKc + dk;       // lane-uniform -> scalar loads
                const float* wq = Wq + o*Cc + c0;
                const float* wk = Wk + o*Cc + c0;
                const float* wv = Wv + o*Cc + c0;
#pragma unroll
                for (int j = 0; j < 8; ++j) {
                    qv[dk] = fmaf(wq[j], f8[j], qv[dk]);
                    kv[dk] = fmaf(wk[j], x8[j], kv[dk]);
                    vv[dk] = fmaf(wv[j], x8[j], vv[dk]);
                }
            }
        }

        int bh = b*NHc + head;
        float* kp = K + (((size_t)bh*Tc + t)*HWc + tid)*DKc;
        float* vp = V + (((size_t)bh*Tc + t)*HWc + tid)*DKc;
        *(float4*)(kp)   = make_float4(kv[0],kv[1],kv[2],kv[3]);
        *(float4*)(kp+4) = make_float4(kv[4],kv[5],kv[6],kv[7]);
        *(float4*)(vp)   = make_float4(vv[0],vv[1],vv[2],vv[3]);
        *(float4*)(vp+4) = make_float4(vv[4],vv[5],vv[6],vv[7]);

        // LayerNorm over (DK,H,W) = 3584 values for this (b,t,head)
        float s1 = 0.f, s2 = 0.f;
#pragma unroll
        for (int dk = 0; dk < DKc; ++dk) { s1 += qv[dk]; s2 += qv[dk]*qv[dk]; }
#pragma unroll
        for (int off = 32; off >= 1; off >>= 1) {
            s1 += __shfl_down(s1, off, 64);
            s2 += __shfl_down(s2, off, 64);
        }
        int wid = tid >> 6, lane = tid & 63;
        if (lane == 0) { rbuf[wid] = s1; rbuf[8+wid] = s2; }
        __syncthreads();
        float S1 = 0.f, S2 = 0.f;
#pragma unroll
        for (int wv2 = 0; wv2 < 7; ++wv2) { S1 += rbuf[wv2]; S2 += rbuf[8+wv2]; }
        const float invN = 1.f / (float)(DKc * HWc);
        float mu   = S1 * invN;
        float var  = S2 * invN - mu*mu;
        float rstd = rsqrtf(var + LN_EPSc);

        float4* Q = (float4*)Qf;
        float qn[DKc];
#pragma unroll
        for (int dk = 0; dk < DKc; ++dk) {
            float gg = gamma[dk*HWc + tid];
            float bb = beta [dk*HWc + tid];
            qn[dk] = ((qv[dk] - mu) * rstd * gg + bb) * INV_SCALE;
        }
        Q[(((size_t)bh*Tc + t)*2 + 0)*HWc + tid] = make_float4(qn[0],qn[1],qn[2],qn[3]);
        Q[(((size_t)bh*Tc + t)*2 + 1)*HWc + tid] = make_float4(qn[4],qn[5],qn[6],qn[7]);
    }

    gridbar(cnt, 256);

    // ================= Phase 2: paired-head attention ======================
    {
        int g   = blk & 1;
        int s   = (blk >> 1) & 7;
        int ha  = (blk >> 4) & 1;
        int b   = blk >> 5;

        int bhA = b*NHc + ha;            int dilA = 2*ha + 1;
        int bhB = b*NHc + (3 - ha);      int dilB = 7 - 2*ha;

        int w = tid % Wc;
        int h = tid / Wc;

        float4* sKA0 = sbuf;            float4* sKA1 = sbuf + HWc;
        float4* sVA0 = sbuf + 2*HWc;    float4* sVA1 = sbuf + 3*HWc;
        float4* sKB0 = sbuf + 4*HWc;    float4* sKB1 = sbuf + 5*HWc;
        float4* sVB0 = sbuf + 6*HWc;    float4* sVB1 = sbuf + 7*HWc;

        const float* kpA = K + ((size_t)bhA*Tc + s)*HWc*DKc;
        const float* vpA = V + ((size_t)bhA*Tc + s)*HWc*DKc;
        const float* kpB = K + ((size_t)bhB*Tc + s)*HWc*DKc;
        const float* vpB = V + ((size_t)bhB*Tc + s)*HWc*DKc;
        sKA0[tid] = *(const float4*)(kpA + tid*DKc);
        sKA1[tid] = *(const float4*)(kpA + tid*DKc + 4);
        sVA0[tid] = *(const float4*)(vpA + tid*DKc);
        sVA1[tid] = *(const float4*)(vpA + tid*DKc + 4);
        sKB0[tid] = *(const float4*)(kpB + tid*DKc);
        sKB1[tid] = *(const float4*)(kpB + tid*DKc + 4);
        sVB0[tid] = *(const float4*)(vpB + tid*DKc);
        sVB1[tid] = *(const float4*)(vpB + tid*DKc + 4);
        __syncthreads();

        int t0 = g*4;
        const float4* Q = (const float4*)Qf;
        attn_item(bhA, dilA, s, t0, tid, w, h, sKA0, sKA1, sVA0, sVA1, Q, Tpart, LMpart);
        attn_item(bhB, dilB, s, t0, tid, w, h, sKB0, sKB1, sVB0, sVB1, Q, Tpart, LMpart);
    }

    gridbar(cnt, 512);

    // ================= Phase 3: combine + output projection ================
    {
        int og  = blk >> 6;
        int bt  = blk & 63;
        int b   = bt >> 3, t = bt & 7;

        float mv[Cc];
        float MS = 0.f;
#pragma unroll
        for (int head = 0; head < NHc; ++head) {
            int bh = b*NHc + head;
            float acc[DKc];
#pragma unroll
            for (int j = 0; j < DKc; ++j) acc[j] = 0.f;
            float lsum = 0.f, mmax = -1e30f;
#pragma unroll
            for (int s = 0; s < Tc; ++s) {
                half8 u = Tpart[(size_t)((bh*Tc + s)*Tc + t)*HWc + tid];
#pragma unroll
                for (int j = 0; j < DKc; ++j) acc[j] += (float)u[j];
                float2 lm = LMpart[(size_t)((bh*Tc + s)*Tc + t)*HWc + tid];
                lsum += lm.x; mmax = fmaxf(mmax, lm.y);
            }
#pragma unroll
            for (int j = 0; j < DKc; ++j) mv[head*DKc + j] = acc[j];
            MS = fmaxf(MS, __expf(mmax) / lsum);
        }
#pragma unroll
        for (int i = 0; i < 8; ++i) {
            int o = og*8 + i;
            float a = 0.f;
#pragma unroll
            for (int c = 0; c < Cc; ++c) a = fmaf(Wo[o*Cc+c], mv[c], a);
            out[((size_t)bt*Cc + o)*HWc + tid] = a * MS;
        }
    }
}

// ---------------------------------------------------------------------------
extern "C" void kernel_launch(void* const* d_in, const int* in_sizes, int n_in,
                              void* d_out, int out_size, void* d_ws, size_t ws_size,
                              hipStream_t stream) {
    const float* first = (const float*)d_in[0];
    const float* x     = (const float*)d_in[1];
    const float* Wq    = (const float*)d_in[2];
    const float* Wk    = (const float*)d_in[3];
    const float* Wv    = (const float*)d_in[4];
    const float* Wo    = (const float*)d_in[5];
    const float* g     = (const float*)d_in[6];
    const float* bta   = (const float*)d_in[7];
    float* out = (float*)d_out;

    float* ws = (float*)d_ws;
    const size_t N5 = (size_t)Bc*NHc*Tc*HWc*DKc;    // 917504 floats
    float*    Q   = ws;                              // N5
    float*    K   = ws +   N5;                       // N5
    float*    V   = ws + 2*N5;                       // N5
    half8*    Tp  = (half8*)(ws + 3*N5);             // 4*N5 floats
    float2*   LMp = (float2*)(ws + 7*N5);            // 2*N5 floats
    unsigned* cnt = (unsigned*)(ws + 9*N5);          // barrier counter
    // total ~33 MB

    hipMemsetAsync(cnt, 0, sizeof(unsigned), stream);
    fused_kernel<<<256, 448, 0, stream>>>(first, x, Wq, Wk, Wv, Wo, g, bta,
                                          Q, K, V, Tp, LMp, out, cnt);
}

// Round 7
// 124.368 us; speedup vs baseline: 1.7903x; 1.7903x over previous
//
#include <hip/hip_runtime.h>

#define Bc 8
#define Tc 8
#define Cc 32
#define Hc 16
#define Wc 28
#define NHc 4
#define DKc 8
#define HWc (Hc*Wc)                  // 448
#define INV_SCALE 0.35355339059327373f
#define LN_EPSc 1e-5f

typedef _Float16 half8 __attribute__((ext_vector_type(8)));

// Global layouts:
//   Q     : [bh][t][j4][hw]    float4   (pre-scaled by INV_SCALE)
//   K,V   : [bh][s][hw][dk]    float    (contiguous slice for LDS staging)
//   Tpart : [bh][s][t][hw]     half8    (fp16 partials)
//   LM    : [bh][s][t][hw]     float2   (l = sum exp, m = max score)
//   Tout  : [bh][t][j4][hw]    float4
//   Mprob : [bh][t][hw]        float

// ---------------------------------------------------------------------------
// Kernel 1: QKV projection + fused LayerNorm of q.
// grid = 256, 448 threads.  blk = head*64 + bt (XCD co-location of the
// 4 blocks sharing one bt slice of first/x).
// ---------------------------------------------------------------------------
__global__ __launch_bounds__(448) void qkv_ln_kernel(
    const float* __restrict__ first, const float* __restrict__ x,
    const float* __restrict__ Wq, const float* __restrict__ Wk,
    const float* __restrict__ Wv,
    const float* __restrict__ gamma, const float* __restrict__ beta,
    float4* __restrict__ Q, float* __restrict__ K, float* __restrict__ V)
{
    int blk  = blockIdx.x;           // head*64 + bt
    int head = blk >> 6;
    int bt   = blk & 63;             // b*T + t
    int t    = bt % Tc;
    int b    = bt / Tc;
    int tid  = threadIdx.x;          // h*W + w

    const float* fp = first + (size_t)bt * Cc * HWc + tid;
    const float* xp = x     + (size_t)bt * Cc * HWc + tid;
    float fv[Cc], xv[Cc];
#pragma unroll
    for (int c = 0; c < Cc; ++c) { fv[c] = fp[c*HWc]; xv[c] = xp[c*HWc]; }

    float qv[DKc], kv[DKc], vv[DKc];
#pragma unroll
    for (int dk = 0; dk < DKc; ++dk) {
        int o = head*DKc + dk;       // lane-uniform -> scalar loads of weights
        float aq = 0.f, ak = 0.f, av = 0.f;
#pragma unroll
        for (int c = 0; c < Cc; ++c) {
            aq = fmaf(Wq[o*Cc+c], fv[c], aq);
            ak = fmaf(Wk[o*Cc+c], xv[c], ak);
            av = fmaf(Wv[o*Cc+c], xv[c], av);
        }
        qv[dk] = aq; kv[dk] = ak; vv[dk] = av;
    }

    int bh = b*NHc + head;
    float* kp = K + (((size_t)bh*Tc + t)*HWc + tid)*DKc;
    float* vp = V + (((size_t)bh*Tc + t)*HWc + tid)*DKc;
    *(float4*)(kp)   = make_float4(kv[0],kv[1],kv[2],kv[3]);
    *(float4*)(kp+4) = make_float4(kv[4],kv[5],kv[6],kv[7]);
    *(float4*)(vp)   = make_float4(vv[0],vv[1],vv[2],vv[3]);
    *(float4*)(vp+4) = make_float4(vv[4],vv[5],vv[6],vv[7]);

    // LayerNorm over (DK,H,W) = 3584 values for this (b,t,head)
    float s1 = 0.f, s2 = 0.f;
#pragma unroll
    for (int dk = 0; dk < DKc; ++dk) { s1 += qv[dk]; s2 += qv[dk]*qv[dk]; }
#pragma unroll
    for (int off = 32; off >= 1; off >>= 1) {
        s1 += __shfl_down(s1, off, 64);
        s2 += __shfl_down(s2, off, 64);
    }
    __shared__ float r1[8], r2[8];
    int wid = tid >> 6, lane = tid & 63;
    if (lane == 0) { r1[wid] = s1; r2[wid] = s2; }
    __syncthreads();
    float S1 = 0.f, S2 = 0.f;
#pragma unroll
    for (int wv2 = 0; wv2 < 7; ++wv2) { S1 += r1[wv2]; S2 += r2[wv2]; }
    const float invN = 1.f / (float)(DKc * HWc);
    float mu   = S1 * invN;
    float var  = S2 * invN - mu*mu;
    float rstd = rsqrtf(var + LN_EPSc);

    float qn[DKc];
#pragma unroll
    for (int dk = 0; dk < DKc; ++dk) {
        float gg = gamma[dk*HWc + tid];
        float bb = beta [dk*HWc + tid];
        qn[dk] = ((qv[dk] - mu) * rstd * gg + bb) * INV_SCALE;  // pre-scale
    }
    Q[(((size_t)bh*Tc + t)*2 + 0)*HWc + tid] = make_float4(qn[0],qn[1],qn[2],qn[3]);
    Q[(((size_t)bh*Tc + t)*2 + 1)*HWc + tid] = make_float4(qn[4],qn[5],qn[6],qn[7]);
}

// ---------------------------------------------------------------------------
// One attention work item: (bh, s, t-quarter), t_batch = 2, K/V in LDS.
// ---------------------------------------------------------------------------
__device__ __forceinline__ void attn_item(
    int bh, int dil, int s, int t0, int tid, int w, int h,
    const float4* sK0, const float4* sK1,
    const float4* sV0, const float4* sV1,
    const float4* __restrict__ Q,
    half8* __restrict__ Tpart, float2* __restrict__ LMpart)
{
    float4 q0[2], q1[2];
    const float4* qb = Q + (size_t)bh*Tc*2*HWc + tid;
#pragma unroll
    for (int j = 0; j < 2; ++j) {
        q0[j] = qb[((t0+j)*2+0)*HWc];
        q1[j] = qb[((t0+j)*2+1)*HWc];
    }

    float4 a0[2], a1[2];
    float l[2], m[2];
#pragma unroll
    for (int j = 0; j < 2; ++j) {
        a0[j] = make_float4(0.f,0.f,0.f,0.f);
        a1[j] = make_float4(0.f,0.f,0.f,0.f);
        l[j] = 0.f; m[j] = -1e30f;
    }

    for (int dy = -3; dy <= 3; ++dy) {
        int hy = h + dy*dil;
        if ((unsigned)hy >= (unsigned)Hc) continue;   // exec-mask row skip
        int rowbase = hy*Wc;
#pragma unroll
        for (int dx = -3; dx <= 3; ++dx) {
            int wx = w + dx*dil;
            int wcl = min(max(wx, 0), Wc-1);
            bool cv = (unsigned)wx < (unsigned)Wc;
            float bias = cv ? 0.f : -1e30f;
            float mask = cv ? 1.f : 0.f;
            int idx = rowbase + wcl;
            float4 k0 = sK0[idx], k1 = sK1[idx];
            float4 v0 = sV0[idx], v1 = sV1[idx];
#pragma unroll
            for (int j = 0; j < 2; ++j) {
                float sc = q0[j].x*k0.x + q0[j].y*k0.y + q0[j].z*k0.z + q0[j].w*k0.w
                         + q1[j].x*k1.x + q1[j].y*k1.y + q1[j].z*k1.z + q1[j].w*k1.w;
                float msc = sc + bias;
                m[j] = fmaxf(m[j], msc);
                l[j] += __expf(msc);
                float z = sc * mask;
                a0[j].x = fmaf(z, v0.x, a0[j].x);
                a0[j].y = fmaf(z, v0.y, a0[j].y);
                a0[j].z = fmaf(z, v0.z, a0[j].z);
                a0[j].w = fmaf(z, v0.w, a0[j].w);
                a1[j].x = fmaf(z, v1.x, a1[j].x);
                a1[j].y = fmaf(z, v1.y, a1[j].y);
                a1[j].z = fmaf(z, v1.z, a1[j].z);
                a1[j].w = fmaf(z, v1.w, a1[j].w);
            }
        }
    }

    half8*  tp  = Tpart  + (size_t)(bh*Tc + s)*Tc*HWc + tid;
    float2* lmp = LMpart + (size_t)(bh*Tc + s)*Tc*HWc + tid;
#pragma unroll
    for (int j = 0; j < 2; ++j) {
        half8 hv;
        hv[0] = (_Float16)a0[j].x; hv[1] = (_Float16)a0[j].y;
        hv[2] = (_Float16)a0[j].z; hv[3] = (_Float16)a0[j].w;
        hv[4] = (_Float16)a1[j].x; hv[5] = (_Float16)a1[j].y;
        hv[6] = (_Float16)a1[j].z; hv[7] = (_Float16)a1[j].w;
        tp [(t0+j)*HWc] = hv;
        lmp[(t0+j)*HWc] = make_float2(l[j], m[j]);
    }
}

// ---------------------------------------------------------------------------
// Kernel 2: attention, complementary-head paired, t_batch = 2.
// grid = 512 blocks (= 2 blocks/CU resident), 448 threads.
// blk = ((b*2 + ha)*8 + s)*4 + tq ; item A = head ha, item B = head 3-ha.
// Per-block row-work: 8.625 (ha=0) vs 8.0 (ha=1) -> balanced +-4%.
// LDS 57344 B/block -> 2 blocks/CU = 112 KB <= 160 KB.
// ---------------------------------------------------------------------------
__global__ __launch_bounds__(448, 4) void attn_kernel(
    const float4* __restrict__ Q, const float* __restrict__ K,
    const float* __restrict__ V,
    half8* __restrict__ Tpart, float2* __restrict__ LMpart)
{
    int blk = blockIdx.x;
    int tq  = blk & 3;               // t-quarter
    int s   = (blk >> 2) & 7;
    int ha  = (blk >> 5) & 1;
    int b   = blk >> 6;

    int bhA = b*NHc + ha;            int dilA = 2*ha + 1;
    int bhB = b*NHc + (3 - ha);      int dilB = 7 - 2*ha;

    int tid = threadIdx.x;           // h*W + w
    int w = tid % Wc;
    int h = tid / Wc;

    __shared__ float4 sKA0[HWc], sKA1[HWc], sVA0[HWc], sVA1[HWc];
    __shared__ float4 sKB0[HWc], sKB1[HWc], sVB0[HWc], sVB1[HWc];  // 57344 B

    {
        const float* kpA = K + ((size_t)bhA*Tc + s)*HWc*DKc;
        const float* vpA = V + ((size_t)bhA*Tc + s)*HWc*DKc;
        const float* kpB = K + ((size_t)bhB*Tc + s)*HWc*DKc;
        const float* vpB = V + ((size_t)bhB*Tc + s)*HWc*DKc;
        sKA0[tid] = *(const float4*)(kpA + tid*DKc);
        sKA1[tid] = *(const float4*)(kpA + tid*DKc + 4);
        sVA0[tid] = *(const float4*)(vpA + tid*DKc);
        sVA1[tid] = *(const float4*)(vpA + tid*DKc + 4);
        sKB0[tid] = *(const float4*)(kpB + tid*DKc);
        sKB1[tid] = *(const float4*)(kpB + tid*DKc + 4);
        sVB0[tid] = *(const float4*)(vpB + tid*DKc);
        sVB1[tid] = *(const float4*)(vpB + tid*DKc + 4);
    }
    __syncthreads();

    int t0 = tq*2;
    attn_item(bhA, dilA, s, t0, tid, w, h, sKA0, sKA1, sVA0, sVA1, Q, Tpart, LMpart);
    attn_item(bhB, dilB, s, t0, tid, w, h, sKB0, sKB1, sVB0, sVB1, Q, Tpart, LMpart);
}

// ---------------------------------------------------------------------------
// Kernel 2b: combine s-partials.  grid = B*NH*T = 256 blocks, 448 threads.
// ---------------------------------------------------------------------------
__global__ __launch_bounds__(448) void combine_kernel(
    const half8* __restrict__ Tpart, const float2* __restrict__ LMpart,
    float4* __restrict__ Tout, float* __restrict__ Mprob)
{
    int blk = blockIdx.x;            // bh*8 + t
    int t   = blk & 7;
    int bh  = blk >> 3;
    int tid = threadIdx.x;           // hw

    float s0x=0.f,s0y=0.f,s0z=0.f,s0w=0.f;
    float s1x=0.f,s1y=0.f,s1z=0.f,s1w=0.f;
    float lsum = 0.f, mmax = -1e30f;
#pragma unroll
    for (int s = 0; s < Tc; ++s) {
        half8 u = Tpart[(size_t)((bh*Tc + s)*Tc + t)*HWc + tid];
        s0x += (float)u[0]; s0y += (float)u[1]; s0z += (float)u[2]; s0w += (float)u[3];
        s1x += (float)u[4]; s1y += (float)u[5]; s1z += (float)u[6]; s1w += (float)u[7];
        float2 lm = LMpart[(size_t)((bh*Tc + s)*Tc + t)*HWc + tid];
        lsum += lm.x; mmax = fmaxf(mmax, lm.y);
    }
    Tout[(size_t)((bh*Tc + t)*2 + 0)*HWc + tid] = make_float4(s0x,s0y,s0z,s0w);
    Tout[(size_t)((bh*Tc + t)*2 + 1)*HWc + tid] = make_float4(s1x,s1y,s1z,s1w);
    Mprob[(size_t)(bh*Tc + t)*HWc + tid] = __expf(mmax) / lsum;
}

// ---------------------------------------------------------------------------
// Kernel 3: output projection: out = (M_T @ Wo^T) * M_S
// grid = 256 blocks, 448 threads.  blk = og*64 + bt (XCD co-location).
// ---------------------------------------------------------------------------
__global__ __launch_bounds__(448) void outproj_kernel(
    const float4* __restrict__ Tout, const float* __restrict__ Mprob,
    const float* __restrict__ Wo, float* __restrict__ out)
{
    int blk = blockIdx.x;            // og*64 + bt
    int og  = blk >> 6;
    int bt  = blk & 63;
    int b   = bt / Tc, t = bt % Tc;
    int tid = threadIdx.x;           // h*W + w

    float mv[Cc];
    float MS = 0.f;
#pragma unroll
    for (int head = 0; head < NHc; ++head) {
        int bh = b*NHc + head;
        float4 u0 = Tout[(size_t)((bh*Tc + t)*2 + 0)*HWc + tid];
        float4 u1 = Tout[(size_t)((bh*Tc + t)*2 + 1)*HWc + tid];
        mv[head*8+0]=u0.x; mv[head*8+1]=u0.y; mv[head*8+2]=u0.z; mv[head*8+3]=u0.w;
        mv[head*8+4]=u1.x; mv[head*8+5]=u1.y; mv[head*8+6]=u1.z; mv[head*8+7]=u1.w;
        MS = fmaxf(MS, Mprob[(size_t)(bh*Tc + t)*HWc + tid]);
    }
#pragma unroll
    for (int i = 0; i < 8; ++i) {
        int o = og*8 + i;
        float acc = 0.f;
#pragma unroll
        for (int c = 0; c < Cc; ++c) acc = fmaf(Wo[o*Cc+c], mv[c], acc);
        out[((size_t)bt*Cc + o)*HWc + tid] = acc * MS;
    }
}

// ---------------------------------------------------------------------------
extern "C" void kernel_launch(void* const* d_in, const int* in_sizes, int n_in,
                              void* d_out, int out_size, void* d_ws, size_t ws_size,
                              hipStream_t stream) {
    const float* first = (const float*)d_in[0];
    const float* x     = (const float*)d_in[1];
    const float* Wq    = (const float*)d_in[2];
    const float* Wk    = (const float*)d_in[3];
    const float* Wv    = (const float*)d_in[4];
    const float* Wo    = (const float*)d_in[5];
    const float* g     = (const float*)d_in[6];
    const float* bta   = (const float*)d_in[7];
    float* out = (float*)d_out;

    float* ws = (float*)d_ws;
    const size_t N5 = (size_t)Bc*NHc*Tc*HWc*DKc;    // 917504 floats
    float4* Q   = (float4*)ws;                       // N5 floats
    float*  K   = ws +   N5;                         // N5
    float*  V   = ws + 2*N5;                         // N5
    float4* Tt  = (float4*)(ws + 3*N5);              // N5 (combined Tout)
    float*  Mp  = ws + 4*N5;                         // N5/8
    half8*  Tp  = (half8*)(ws + 4*N5 + N5/8);        // Tpart: 4*N5 floats
    float2* LMp = (float2*)(ws + 8*N5 + N5/8);       // LM: 2*N5 floats
    // total: ~37 MB

    qkv_ln_kernel <<<Bc*Tc*NHc, 448, 0, stream>>>(first, x, Wq, Wk, Wv, g, bta, Q, K, V);
    attn_kernel   <<<512,       448, 0, stream>>>(Q, K, V, Tp, LMp);
    combine_kernel<<<Bc*NHc*Tc, 448, 0, stream>>>(Tp, LMp, Tt, Mp);
    outproj_kernel<<<256,       448, 0, stream>>>(Tt, Mp, Wo, out);
}